// Round 4
// baseline (373.186 us; speedup 1.0000x reference)
//
#include <hip/hip_runtime.h>
#include <stdint.h>
#include <type_traits>

// Problem constants (from reference): B,T,X,E,H,L = 4096,32,256,32,512,2
#define B_SZ 4096
#define T_SZ 32
#define X_SZ 256
#define E_SZ 32
#define H_SZ 512
#define BM   128     // batch rows per block

typedef __attribute__((ext_vector_type(8))) short  short8;   // 8 bf16 = 4 VGPR
typedef __attribute__((ext_vector_type(4))) float  floatx4;

// v_cvt_pk_bf16_f32: D[15:0]=bf16(a), D[31:16]=bf16(b), RNE (gfx950 HW instr)
__device__ __forceinline__ unsigned pk2(float a, float b) {
  unsigned r;
  asm("v_cvt_pk_bf16_f32 %0, %1, %2" : "=v"(r) : "v"(a), "v"(b));
  return r;
}

// ---------------------------------------------------------------------------
// Prep: fp32 weights -> bf16 MFMA B-fragments via LDS transpose. (unchanged)
// One block per chunk (32 k x 512 n). 1312 chunks total:
//   c in [0,288):    layer-1, c = e*9+kt. kt==0 -> masked W1t rows 0..31;
//                    kt>=1 -> W1x rows (kt-1)*32 .. +31.   out: wcat.
//   c in [288,1312): hidden, c-288 = (layer*32+e)*16 + kt. out: whf.
// Unit layout (contract with mlp_kernel): u = nb*64 + l,
//   n = nb*16 + (l&15), local k0 = (l>>4)*8, dword p covers k = k0+2p, k0+2p+1.
// ---------------------------------------------------------------------------
__global__ __launch_bounds__(256) void prep_kernel(
    const float* __restrict__ W1t, const float* __restrict__ W1x,
    const int* __restrict__ masks, const float* __restrict__ Wh,
    uint4* __restrict__ wcat, uint4* __restrict__ whf) {
  __shared__ unsigned lds[16 * 516];           // 33 KB
  const int c = blockIdx.x;
  const int t = threadIdx.x;

  const float* base;                           // row 0 of this chunk's 32 rows
  bool needMask = false;
  int e1 = 0;
  if (c >= 288) {
    int cc = c - 288;
    int le = cc >> 4, kt = cc & 15;            // le = layer*32 + e
    base = Wh + ((size_t)le * H_SZ + kt * 32) * H_SZ;
  } else {
    int e = c / 9, kt = c - e * 9;
    e1 = e;
    if (kt == 0) { base = W1t + (size_t)e * T_SZ * H_SZ; needMask = true; }
    else          base = W1x + ((size_t)e * X_SZ + (kt - 1) * 32) * H_SZ;
  }

#pragma unroll
  for (int i = 0; i < 8; ++i) {
    int g  = i * 256 + t;
    int k2 = g >> 7, np = g & 127;             // k2: wave-uniform
    const float* r0 = base + (size_t)(2 * k2) * H_SZ + np * 4;
    float4 a = *(const float4*)r0;
    float4 b = *(const float4*)(r0 + H_SZ);
    if (needMask) {
      float s0 = (float)masks[e1 * T_SZ + 2 * k2];
      float s1 = (float)masks[e1 * T_SZ + 2 * k2 + 1];
      a.x *= s0; a.y *= s0; a.z *= s0; a.w *= s0;
      b.x *= s1; b.y *= s1; b.z *= s1; b.w *= s1;
    }
    *(uint4*)&lds[k2 * 516 + np * 4] =
        make_uint4(pk2(a.x, b.x), pk2(a.y, b.y), pk2(a.z, b.z), pk2(a.w, b.w));
  }
  __syncthreads();

  uint4* outp = (c < 288) ? (wcat + (size_t)c * 2048)
                          : (whf + (size_t)(c - 288) * 2048);
  const int w = t >> 6, l = t & 63, q = l >> 4, l16 = l & 15;
#pragma unroll
  for (int j = 0; j < 8; ++j) {
    int nb = w * 8 + j;
    int n  = nb * 16 + l16;
    int kb = 4 * q;
    uint4 v;
    v.x = lds[(kb + 0) * 516 + n];
    v.y = lds[(kb + 1) * 516 + n];
    v.z = lds[(kb + 2) * 516 + n];
    v.w = lds[(kb + 3) * 516 + n];
    outp[nb * 64 + l] = v;                     // 16B/lane, lanes consecutive
  }
}

// ---------------------------------------------------------------------------
// Fused MLP v4: BM=128, 1024 threads (16 waves), 1 block/CU, 4 waves/SIMD.
// Wave w owns cols [32w, 32w+32) over all 128 rows: acc[8][2] (64 AGPR).
// A buffer is FRAGMENT-MAJOR: unit(kt,mb,lane) at ((kt*8+mb)*64+lane)*16
// holds A[m0 + mb*16 + (lane&15)][kt*32 + (lane>>4)*8 .. +7] as 8 bf16.
//  -> gemm ds_read_b128 is 64 consecutive lanes x 16B = conflict-free.
//  -> epilogue of wave w writes exactly next-layer chunk kt'=w (cols 32w..).
// Weight loads: 2 per wave per chunk (u0 = w*128+l, +64), 1-chunk prefetch.
// Block map: all 32 CUs of an XCD run the same expert concurrently.
// ---------------------------------------------------------------------------
__global__ __launch_bounds__(1024, 4) void mlp_kernel(
    const float* __restrict__ theta, const float* __restrict__ x,
    const short8* __restrict__ wcat, const short8* __restrict__ whf,
    const float* __restrict__ b1, const float* __restrict__ a1,
    const float* __restrict__ bh, const float* __restrict__ ah,
    const float* __restrict__ Wo, const float* __restrict__ bo,
    float* __restrict__ out) {
  __shared__ __align__(16) char smA[16 * 8 * 64 * 16];   // 131072 B, 1 block/CU
  const int tid = threadIdx.x;
  const int bid = blockIdx.x;
  const int xcd = bid & 7;
  const int t8  = bid >> 3;                       // per-XCD sequence 0..127
  const int e   = xcd * 4 + (t8 >> 5);            // 32 consecutive blocks/expert
  const int m0  = (t8 & 31) * BM;
  const int w   = tid >> 6, l = tid & 63, l16 = l & 15, quad = l >> 4;

  // ---- stage A0 = [theta | x] bf16, directly in fragment order ----
  // unit g: lane=g&63, mb=(g>>6)&7, kt=g>>9; row = mb*16+(lane&15),
  // k = kt*32 + (lane>>4)*8 .. +7  (kt==0 -> theta cols, else x cols).
  for (int g = tid; g < 9 * 512; g += 1024) {
    int lane = g & 63, mb = (g >> 6) & 7, kt = g >> 9;
    int row  = m0 + mb * 16 + (lane & 15);
    int ks   = (lane >> 4) * 8;
    const float* src = (kt == 0)
                           ? (theta + (size_t)row * T_SZ + ks)
                           : (x + (size_t)row * X_SZ + (kt - 1) * 32 + ks);
    float4 a = *(const float4*)src;
    float4 b = *(const float4*)(src + 4);
    *(uint4*)(smA + (size_t)g * 16) =
        make_uint4(pk2(a.x, a.y), pk2(a.z, a.w), pk2(b.x, b.y), pk2(b.z, b.w));
  }
  __syncthreads();

  floatx4 acc[8][2];
  const int u0 = w * 128 + l;                     // weight unit index (nb=2w)

  // GEMM over NKT K-chunks of 32, fully unrolled. Weights 1-chunk prefetch.
  auto gemm = [&](const short8* wbase, auto nktc) {
    constexpr int NKT = decltype(nktc)::value;
#pragma unroll
    for (int mb = 0; mb < 8; ++mb)
#pragma unroll
      for (int i = 0; i < 2; ++i) acc[mb][i] = (floatx4)(0.f);
    short8 bA[2], bB[2];
    bA[0] = wbase[u0];
    bA[1] = wbase[u0 + 64];
    const short8* wu = wbase;
#pragma unroll
    for (int kt = 0; kt < NKT; ++kt) {
      if (kt + 1 < NKT) {                         // prefetch next chunk
        const short8* wn = wu + 2048;
        if (kt & 1) { bA[0] = wn[u0]; bA[1] = wn[u0 + 64]; }
        else        { bB[0] = wn[u0]; bB[1] = wn[u0 + 64]; }
      }
      // two half-groups of 4 A-fragments each (caps VGPR, keeps ILP)
#pragma unroll
      for (int h = 0; h < 2; ++h) {
        short8 af[4];
#pragma unroll
        for (int m = 0; m < 4; ++m)
          af[m] = *(const short8*)(smA + ((kt * 8 + h * 4 + m) * 64 + l) * 16);
#pragma unroll
        for (int m = 0; m < 4; ++m)
#pragma unroll
          for (int i = 0; i < 2; ++i)
            acc[h * 4 + m][i] = __builtin_amdgcn_mfma_f32_16x16x32_bf16(
                af[m], (kt & 1) ? bB[i] : bA[i], acc[h * 4 + m][i], 0, 0, 0);
      }
      wu += 2048;
    }
  };

  // bias + PReLU + bf16 pair-pack (shfl_xor 1) + write into fragment-major A.
  // Value at (row R = mb*16+quad*4+r, col C = w*32+i*16+l16) goes to unit
  // (w*8+mb)*64 + lane', lane' = (R&15) + (i*2 + (l16>>3))*16, dword (l16&6)/2.
  auto epi_store = [&](const float* bias, const float* slope) {
    float bb[2], aa[2];
#pragma unroll
    for (int i = 0; i < 2; ++i) {
      int col = w * 32 + i * 16 + l16;
      bb[i] = bias[col];
      aa[i] = slope[col];
    }
    __syncthreads();   // everyone done READING A before we overwrite
#pragma unroll
    for (int mb = 0; mb < 8; ++mb) {
#pragma unroll
      for (int i = 0; i < 2; ++i) {
        unsigned dw[4];
#pragma unroll
        for (int r = 0; r < 4; ++r) {
          float v = acc[mb][i][r] + bb[i];
          v = v >= 0.f ? v : aa[i] * v;
          float o  = __shfl_xor(v, 1, 64);
          float lo = (l16 & 1) ? o : v;
          float hi = (l16 & 1) ? v : o;
          dw[r] = pk2(lo, hi);
        }
        int rbase = (l16 & 1) * 2;               // even lanes rows 0,1; odd 2,3
        char* ubase = smA + ((w * 8 + mb) * 64) * 16 + (l16 & 6) * 2;
#pragma unroll
        for (int rr = 0; rr < 2; ++rr) {
          int lane_p = quad * 4 + rbase + rr + (i * 2 + (l16 >> 3)) * 16;
          *(unsigned*)(ubase + lane_p * 16) = dw[rbase + rr];
        }
      }
    }
    __syncthreads();
  };

  // ---- layer 1: K = 288 (9 chunks) ----
  gemm(wcat + (size_t)e * 9 * 2048, std::integral_constant<int, 9>{});
  epi_store(b1 + (size_t)e * H_SZ, a1 + (size_t)e * H_SZ);
  // ---- hidden layer 0: K = 512 (16 chunks) ----
  gemm(whf + (size_t)e * 16 * 2048, std::integral_constant<int, 16>{});
  epi_store(bh + (size_t)e * H_SZ, ah + (size_t)e * H_SZ);
  // ---- hidden layer 1 + fused output dot (fp32, no bf16 rounding) ----
  gemm(whf + (size_t)(E_SZ + e) * 16 * 2048, std::integral_constant<int, 16>{});
  {
    float bb[2], aa[2], wo[2];
#pragma unroll
    for (int i = 0; i < 2; ++i) {
      int col = w * 32 + i * 16 + l16;
      bb[i] = bh[(size_t)(E_SZ + e) * H_SZ + col];
      aa[i] = ah[(size_t)(E_SZ + e) * H_SZ + col];
      wo[i] = Wo[(size_t)e * H_SZ + col];
    }
    float ps[8][4];
#pragma unroll
    for (int mb = 0; mb < 8; ++mb)
#pragma unroll
      for (int r = 0; r < 4; ++r) ps[mb][r] = 0.f;
#pragma unroll
    for (int mb = 0; mb < 8; ++mb)
#pragma unroll
      for (int i = 0; i < 2; ++i)
#pragma unroll
        for (int r = 0; r < 4; ++r) {
          float v = acc[mb][i][r] + bb[i];
          v = v >= 0.f ? v : aa[i] * v;
          ps[mb][r] += v * wo[i];
        }
    // reduce over the 16 lanes of each quad (cols within this wave's slice)
#pragma unroll
    for (int d = 1; d < 16; d <<= 1)
#pragma unroll
      for (int mb = 0; mb < 8; ++mb)
#pragma unroll
        for (int r = 0; r < 4; ++r) ps[mb][r] += __shfl_xor(ps[mb][r], d, 64);
    __syncthreads();                 // done reading A; reuse its storage
    float* scratch = (float*)smA;    // [128 rows][16 waves]
    if (l16 == 0) {
#pragma unroll
      for (int mb = 0; mb < 8; ++mb)
#pragma unroll
        for (int r = 0; r < 4; ++r)
          scratch[(mb * 16 + quad * 4 + r) * 16 + w] = ps[mb][r];
    }
    __syncthreads();
    if (tid < BM) {
      float s = 0.f;
#pragma unroll
      for (int ww = 0; ww < 16; ++ww) s += scratch[tid * 16 + ww];
      out[(size_t)(m0 + tid) * E_SZ + e] = s + bo[e];
    }
  }
}

// ---------------------------------------------------------------------------
extern "C" void kernel_launch(void* const* d_in, const int* in_sizes, int n_in,
                              void* d_out, int out_size, void* d_ws, size_t ws_size,
                              hipStream_t stream) {
  const float* theta = (const float*)d_in[0];
  const float* x     = (const float*)d_in[1];
  const int*   masks = (const int*)d_in[2];
  const float* W1t   = (const float*)d_in[3];
  const float* W1x   = (const float*)d_in[4];
  const float* b1    = (const float*)d_in[5];
  const float* a1    = (const float*)d_in[6];
  const float* Wh    = (const float*)d_in[7];
  const float* bh    = (const float*)d_in[8];
  const float* ah    = (const float*)d_in[9];
  const float* Wo    = (const float*)d_in[10];
  const float* bo    = (const float*)d_in[11];
  float* out = (float*)d_out;

  // ws layout: [0, 9.4MB) layer-1 frags; [9.4MB, 43MB) hidden frags.
  uint4* wcat = (uint4*)d_ws;
  uint4* whf  = (uint4*)((char*)d_ws + (size_t)E_SZ * 9 * 2048 * 16);

  // 288 layer-1 chunks + 1024 hidden chunks, one block each
  prep_kernel<<<1312, 256, 0, stream>>>(W1t, W1x, masks, Wh, wcat, whf);
  // 1024 blocks: 32 m-tiles x 32 experts, 1024 threads each
  mlp_kernel<<<1024, 1024, 0, stream>>>(theta, x, (const short8*)wcat,
                                        (const short8*)whf, b1, a1, bh, ah, Wo,
                                        bo, out);
}

// Round 5
// 348.448 us; speedup vs baseline: 1.0710x; 1.0710x over previous
//
#include <hip/hip_runtime.h>
#include <stdint.h>
#include <type_traits>

// Problem constants (from reference): B,T,X,E,H,L = 4096,32,256,32,512,2
#define B_SZ 4096
#define T_SZ 32
#define X_SZ 256
#define E_SZ 32
#define H_SZ 512
#define BM   128     // batch rows per block

typedef __attribute__((ext_vector_type(8))) short  short8;   // 8 bf16 = 4 VGPR
typedef __attribute__((ext_vector_type(4))) float  floatx4;

// v_cvt_pk_bf16_f32: D[15:0]=bf16(a), D[31:16]=bf16(b), RNE (gfx950 HW instr)
__device__ __forceinline__ unsigned pk2(float a, float b) {
  unsigned r;
  asm("v_cvt_pk_bf16_f32 %0, %1, %2" : "=v"(r) : "v"(a), "v"(b));
  return r;
}

// ---------------------------------------------------------------------------
// Prep: fp32 weights -> bf16 MFMA B-fragments via LDS transpose. (unchanged)
// One block per chunk (32 k x 512 n). 1312 chunks total:
//   c in [0,288):    layer-1, c = e*9+kt. kt==0 -> masked W1t rows 0..31;
//                    kt>=1 -> W1x rows (kt-1)*32 .. +31.   out: wcat.
//   c in [288,1312): hidden, c-288 = (layer*32+e)*16 + kt. out: whf.
// Unit layout (contract with mlp_kernel): u = nb*64 + l,
//   n = nb*16 + (l&15), local k0 = (l>>4)*8, dword p covers k = k0+2p, k0+2p+1.
// ---------------------------------------------------------------------------
__global__ __launch_bounds__(256) void prep_kernel(
    const float* __restrict__ W1t, const float* __restrict__ W1x,
    const int* __restrict__ masks, const float* __restrict__ Wh,
    uint4* __restrict__ wcat, uint4* __restrict__ whf) {
  __shared__ unsigned lds[16 * 516];           // 33 KB
  const int c = blockIdx.x;
  const int t = threadIdx.x;

  const float* base;                           // row 0 of this chunk's 32 rows
  bool needMask = false;
  int e1 = 0;
  if (c >= 288) {
    int cc = c - 288;
    int le = cc >> 4, kt = cc & 15;            // le = layer*32 + e
    base = Wh + ((size_t)le * H_SZ + kt * 32) * H_SZ;
  } else {
    int e = c / 9, kt = c - e * 9;
    e1 = e;
    if (kt == 0) { base = W1t + (size_t)e * T_SZ * H_SZ; needMask = true; }
    else          base = W1x + ((size_t)e * X_SZ + (kt - 1) * 32) * H_SZ;
  }

#pragma unroll
  for (int i = 0; i < 8; ++i) {
    int g  = i * 256 + t;
    int k2 = g >> 7, np = g & 127;             // k2: wave-uniform
    const float* r0 = base + (size_t)(2 * k2) * H_SZ + np * 4;
    float4 a = *(const float4*)r0;
    float4 b = *(const float4*)(r0 + H_SZ);
    if (needMask) {
      float s0 = (float)masks[e1 * T_SZ + 2 * k2];
      float s1 = (float)masks[e1 * T_SZ + 2 * k2 + 1];
      a.x *= s0; a.y *= s0; a.z *= s0; a.w *= s0;
      b.x *= s1; b.y *= s1; b.z *= s1; b.w *= s1;
    }
    *(uint4*)&lds[k2 * 516 + np * 4] =
        make_uint4(pk2(a.x, b.x), pk2(a.y, b.y), pk2(a.z, b.z), pk2(a.w, b.w));
  }
  __syncthreads();

  uint4* outp = (c < 288) ? (wcat + (size_t)c * 2048)
                          : (whf + (size_t)(c - 288) * 2048);
  const int w = t >> 6, l = t & 63, q = l >> 4, l16 = l & 15;
#pragma unroll
  for (int j = 0; j < 8; ++j) {
    int nb = w * 8 + j;
    int n  = nb * 16 + l16;
    int kb = 4 * q;
    uint4 v;
    v.x = lds[(kb + 0) * 516 + n];
    v.y = lds[(kb + 1) * 516 + n];
    v.z = lds[(kb + 2) * 516 + n];
    v.w = lds[(kb + 3) * 516 + n];
    outp[nb * 64 + l] = v;                     // 16B/lane, lanes consecutive
  }
}

// ---------------------------------------------------------------------------
// Fused MLP v5: BM=128, 1024 threads (16 waves), 1 block/CU, 4 waves/SIMD.
// Wave w: row-half rh=w&1 (rows rh*64..+63), col-strip wc=w>>1 (cols
// wc*64..+63). acc[4][4] = 64 AGPR; arch side af[4]+b[8]+addr ~ 60 VGPR ->
// fits the 128-unified/wave budget (R0-proven shape; v4's spills eliminated).
// Per K-chunk per wave: 4 af ds_read_b128 (conflict-free, fragment-major A),
// 4 weight loads (L2), 16 MFMA -> 256 B LDS/MFMA; per CU per chunk-round:
// MFMA 1240cy > LDS 770cy > L2 585cy. MFMA-dominant.
// A buffer FRAGMENT-MAJOR: unit(kt,mb,lane) at ((kt*8+mb)*64+lane)*16 holds
// A[m0+mb*16+(lane&15)][kt*32+(lane>>4)*8 ..+7].
// Block map: all 32 CUs of an XCD run the same expert concurrently.
// ---------------------------------------------------------------------------
__global__ __launch_bounds__(1024, 4) void mlp_kernel(
    const float* __restrict__ theta, const float* __restrict__ x,
    const short8* __restrict__ wcat, const short8* __restrict__ whf,
    const float* __restrict__ b1, const float* __restrict__ a1,
    const float* __restrict__ bh, const float* __restrict__ ah,
    const float* __restrict__ Wo, const float* __restrict__ bo,
    float* __restrict__ out) {
  __shared__ __align__(16) char smA[16 * 8 * 64 * 16];   // 131072 B, 1 block/CU
  const int tid = threadIdx.x;
  const int bid = blockIdx.x;
  const int xcd = bid & 7;
  const int t8  = bid >> 3;                       // per-XCD sequence 0..127
  const int e   = xcd * 4 + (t8 >> 5);            // 32 consecutive blocks/expert
  const int m0  = (t8 & 31) * BM;
  const int w   = tid >> 6, l = tid & 63, l16 = l & 15, quad = l >> 4;
  const int rh  = w & 1;                          // row half (0: rows 0-63)
  const int wc  = w >> 1;                         // col strip (64 cols)

  // ---- stage A0 = [theta | x] bf16, directly in fragment order ----
  // unit g: lane=g&63, mb=(g>>6)&7, kt=g>>9; row = mb*16+(lane&15),
  // k = kt*32 + (lane>>4)*8 .. +7  (kt==0 -> theta cols, else x cols).
  for (int g = tid; g < 9 * 512; g += 1024) {
    int lane = g & 63, mb = (g >> 6) & 7, kt = g >> 9;
    int row  = m0 + mb * 16 + (lane & 15);
    int ks   = (lane >> 4) * 8;
    const float* src = (kt == 0)
                           ? (theta + (size_t)row * T_SZ + ks)
                           : (x + (size_t)row * X_SZ + (kt - 1) * 32 + ks);
    float4 a = *(const float4*)src;
    float4 b = *(const float4*)(src + 4);
    *(uint4*)(smA + (size_t)g * 16) =
        make_uint4(pk2(a.x, a.y), pk2(a.z, a.w), pk2(b.x, b.y), pk2(b.z, b.w));
  }
  __syncthreads();

  floatx4 acc[4][4];
  const int u0   = wc * 256 + l;                  // weight unit index (nb=wc*4)
  const int rh4  = rh * 4;                        // global mb base for this wave

  // GEMM over NKT K-chunks of 32, fully unrolled. Weights 1-chunk prefetch,
  // double-buffered by register renaming (kt&1).
  auto gemm = [&](const short8* wbase, auto nktc) {
    constexpr int NKT = decltype(nktc)::value;
#pragma unroll
    for (int m = 0; m < 4; ++m)
#pragma unroll
      for (int i = 0; i < 4; ++i) acc[m][i] = (floatx4)(0.f);
    short8 bA[4], bB[4];
#pragma unroll
    for (int i = 0; i < 4; ++i) bA[i] = wbase[u0 + i * 64];
    const short8* wu = wbase;
#pragma unroll
    for (int kt = 0; kt < NKT; ++kt) {
      if (kt + 1 < NKT) {                         // prefetch next chunk
        const short8* wn = wu + 2048;
        if (kt & 1) {
#pragma unroll
          for (int i = 0; i < 4; ++i) bA[i] = wn[u0 + i * 64];
        } else {
#pragma unroll
          for (int i = 0; i < 4; ++i) bB[i] = wn[u0 + i * 64];
        }
      }
      short8 af[4];
#pragma unroll
      for (int m = 0; m < 4; ++m)
        af[m] = *(const short8*)(smA + (((kt * 8 + rh4 + m) * 64 + l) << 4));
#pragma unroll
      for (int m = 0; m < 4; ++m)
#pragma unroll
        for (int i = 0; i < 4; ++i)
          acc[m][i] = __builtin_amdgcn_mfma_f32_16x16x32_bf16(
              af[m], (kt & 1) ? bB[i] : bA[i], acc[m][i], 0, 0, 0);
      wu += 2048;
    }
  };

  // bias + PReLU + bf16 pair-pack (shfl_xor 1) + write into fragment-major A.
  // Value (R = rh*64+mb*16+quad*4+r, C = wc*64+i*16+l16) -> unit
  // kt' = wc*2 + (i>>1), mb' = rh4+mb, lane' = (R&15) + ((i*2+(l16>>3))&3)*16,
  // dword (l16&6)>>1.  (verified against reader mapping)
  auto epi_store = [&](const float* bias, const float* slope) {
    float bb[4], aa[4];
#pragma unroll
    for (int i = 0; i < 4; ++i) {
      int col = wc * 64 + i * 16 + l16;
      bb[i] = bias[col];
      aa[i] = slope[col];
    }
    __syncthreads();   // everyone done READING A before we overwrite
#pragma unroll
    for (int mb = 0; mb < 4; ++mb) {
#pragma unroll
      for (int i = 0; i < 4; ++i) {
        unsigned dw[4];
#pragma unroll
        for (int r = 0; r < 4; ++r) {
          float v = acc[mb][i][r] + bb[i];
          v = v >= 0.f ? v : aa[i] * v;
          float o  = __shfl_xor(v, 1, 64);
          float lo = (l16 & 1) ? o : v;
          float hi = (l16 & 1) ? v : o;
          dw[r] = pk2(lo, hi);
        }
        int rbase  = (l16 & 1) * 2;              // even lanes rows 0,1; odd 2,3
        int ktp    = wc * 2 + (i >> 1);
        int mbp    = rh4 + mb;
        int lhi    = ((i * 2 + (l16 >> 3)) & 3) * 16;
        char* ubase = smA + (ktp * 8 + mbp) * 1024 + (l16 & 6) * 2;
#pragma unroll
        for (int rr = 0; rr < 2; ++rr) {
          int lane_p = (quad * 4 + rbase + rr) + lhi;   // R&15 + hi part
          *(unsigned*)(ubase + lane_p * 16) = dw[rbase + rr];
        }
      }
    }
    __syncthreads();
  };

  // ---- layer 1: K = 288 (9 chunks) ----
  gemm(wcat + (size_t)e * 9 * 2048, std::integral_constant<int, 9>{});
  epi_store(b1 + (size_t)e * H_SZ, a1 + (size_t)e * H_SZ);
  // ---- hidden layer 0: K = 512 (16 chunks) ----
  gemm(whf + (size_t)e * 16 * 2048, std::integral_constant<int, 16>{});
  epi_store(bh + (size_t)e * H_SZ, ah + (size_t)e * H_SZ);
  // ---- hidden layer 1 + fused output dot (fp32, no bf16 rounding) ----
  gemm(whf + (size_t)(E_SZ + e) * 16 * 2048, std::integral_constant<int, 16>{});
  {
    float bb[4], aa[4], wo[4];
#pragma unroll
    for (int i = 0; i < 4; ++i) {
      int col = wc * 64 + i * 16 + l16;
      bb[i] = bh[(size_t)(E_SZ + e) * H_SZ + col];
      aa[i] = ah[(size_t)(E_SZ + e) * H_SZ + col];
      wo[i] = Wo[(size_t)e * H_SZ + col];
    }
    float ps[4][4];
#pragma unroll
    for (int m = 0; m < 4; ++m)
#pragma unroll
      for (int r = 0; r < 4; ++r) ps[m][r] = 0.f;
#pragma unroll
    for (int m = 0; m < 4; ++m)
#pragma unroll
      for (int i = 0; i < 4; ++i)
#pragma unroll
        for (int r = 0; r < 4; ++r) {
          float v = acc[m][i][r] + bb[i];
          v = v >= 0.f ? v : aa[i] * v;
          ps[m][r] += v * wo[i];
        }
    // reduce over the 16 lanes of each quad (cols within this wave's strip)
#pragma unroll
    for (int d = 1; d < 16; d <<= 1)
#pragma unroll
      for (int m = 0; m < 4; ++m)
#pragma unroll
        for (int r = 0; r < 4; ++r) ps[m][r] += __shfl_xor(ps[m][r], d, 64);
    __syncthreads();                 // done reading A; reuse its storage
    float* scratch = (float*)smA;    // [128 rows][8 col-strips]
    if (l16 == 0) {
#pragma unroll
      for (int m = 0; m < 4; ++m)
#pragma unroll
        for (int r = 0; r < 4; ++r)
          scratch[(rh * 64 + m * 16 + quad * 4 + r) * 8 + wc] = ps[m][r];
    }
    __syncthreads();
    if (tid < BM) {
      float s = 0.f;
#pragma unroll
      for (int ww = 0; ww < 8; ++ww) s += scratch[tid * 8 + ww];
      out[(size_t)(m0 + tid) * E_SZ + e] = s + bo[e];
    }
  }
}

// ---------------------------------------------------------------------------
extern "C" void kernel_launch(void* const* d_in, const int* in_sizes, int n_in,
                              void* d_out, int out_size, void* d_ws, size_t ws_size,
                              hipStream_t stream) {
  const float* theta = (const float*)d_in[0];
  const float* x     = (const float*)d_in[1];
  const int*   masks = (const int*)d_in[2];
  const float* W1t   = (const float*)d_in[3];
  const float* W1x   = (const float*)d_in[4];
  const float* b1    = (const float*)d_in[5];
  const float* a1    = (const float*)d_in[6];
  const float* Wh    = (const float*)d_in[7];
  const float* bh    = (const float*)d_in[8];
  const float* ah    = (const float*)d_in[9];
  const float* Wo    = (const float*)d_in[10];
  const float* bo    = (const float*)d_in[11];
  float* out = (float*)d_out;

  // ws layout: [0, 9.4MB) layer-1 frags; [9.4MB, 43MB) hidden frags.
  uint4* wcat = (uint4*)d_ws;
  uint4* whf  = (uint4*)((char*)d_ws + (size_t)E_SZ * 9 * 2048 * 16);

  // 288 layer-1 chunks + 1024 hidden chunks, one block each
  prep_kernel<<<1312, 256, 0, stream>>>(W1t, W1x, masks, Wh, wcat, whf);
  // 1024 blocks: 32 m-tiles x 32 experts, 1024 threads each
  mlp_kernel<<<1024, 1024, 0, stream>>>(theta, x, (const short8*)wcat,
                                        (const short8*)whf, b1, a1, bh, ah, Wo,
                                        bo, out);
}

// Round 6
// 327.323 us; speedup vs baseline: 1.1401x; 1.0645x over previous
//
#include <hip/hip_runtime.h>
#include <stdint.h>

// Problem constants (from reference): B,T,X,E,H,L = 4096,32,256,32,512,2
#define B_SZ 4096
#define T_SZ 32
#define X_SZ 256
#define E_SZ 32
#define H_SZ 512
#define BM   128     // batch rows per block

typedef __attribute__((ext_vector_type(8))) short  short8;   // 8 bf16 = 4 VGPR
typedef __attribute__((ext_vector_type(4))) float  floatx4;

// v_cvt_pk_bf16_f32: D[15:0]=bf16(a), D[31:16]=bf16(b), RNE (gfx950 HW instr)
__device__ __forceinline__ unsigned pk2(float a, float b) {
  unsigned r;
  asm("v_cvt_pk_bf16_f32 %0, %1, %2" : "=v"(r) : "v"(a), "v"(b));
  return r;
}

// ---------------------------------------------------------------------------
// Prep: fp32 weights -> bf16 MFMA B-fragments via LDS transpose. (unchanged)
// One block per chunk (32 k x 512 n). 1312 chunks total:
//   c in [0,288):    layer-1, c = e*9+kt. kt==0 -> masked W1t rows 0..31;
//                    kt>=1 -> W1x rows (kt-1)*32 .. +31.   out: wcat.
//   c in [288,1312): hidden, c-288 = (layer*32+e)*16 + kt. out: whf.
// Unit layout (contract with mlp_kernel): u = nb*64 + l,
//   n = nb*16 + (l&15), local k0 = (l>>4)*8, dword p covers k = k0+2p, k0+2p+1.
// ---------------------------------------------------------------------------
__global__ __launch_bounds__(256) void prep_kernel(
    const float* __restrict__ W1t, const float* __restrict__ W1x,
    const int* __restrict__ masks, const float* __restrict__ Wh,
    uint4* __restrict__ wcat, uint4* __restrict__ whf) {
  __shared__ unsigned lds[16 * 516];           // 33 KB
  const int c = blockIdx.x;
  const int t = threadIdx.x;

  const float* base;                           // row 0 of this chunk's 32 rows
  bool needMask = false;
  int e1 = 0;
  if (c >= 288) {
    int cc = c - 288;
    int le = cc >> 4, kt = cc & 15;            // le = layer*32 + e
    base = Wh + ((size_t)le * H_SZ + kt * 32) * H_SZ;
  } else {
    int e = c / 9, kt = c - e * 9;
    e1 = e;
    if (kt == 0) { base = W1t + (size_t)e * T_SZ * H_SZ; needMask = true; }
    else          base = W1x + ((size_t)e * X_SZ + (kt - 1) * 32) * H_SZ;
  }

#pragma unroll
  for (int i = 0; i < 8; ++i) {
    int g  = i * 256 + t;
    int k2 = g >> 7, np = g & 127;             // k2: wave-uniform
    const float* r0 = base + (size_t)(2 * k2) * H_SZ + np * 4;
    float4 a = *(const float4*)r0;
    float4 b = *(const float4*)(r0 + H_SZ);
    if (needMask) {
      float s0 = (float)masks[e1 * T_SZ + 2 * k2];
      float s1 = (float)masks[e1 * T_SZ + 2 * k2 + 1];
      a.x *= s0; a.y *= s0; a.z *= s0; a.w *= s0;
      b.x *= s1; b.y *= s1; b.z *= s1; b.w *= s1;
    }
    *(uint4*)&lds[k2 * 516 + np * 4] =
        make_uint4(pk2(a.x, b.x), pk2(a.y, b.y), pk2(a.z, b.z), pk2(a.w, b.w));
  }
  __syncthreads();

  uint4* outp = (c < 288) ? (wcat + (size_t)c * 2048)
                          : (whf + (size_t)(c - 288) * 2048);
  const int w = t >> 6, l = t & 63, q = l >> 4, l16 = l & 15;
#pragma unroll
  for (int j = 0; j < 8; ++j) {
    int nb = w * 8 + j;
    int n  = nb * 16 + l16;
    int kb = 4 * q;
    uint4 v;
    v.x = lds[(kb + 0) * 516 + n];
    v.y = lds[(kb + 1) * 516 + n];
    v.z = lds[(kb + 2) * 516 + n];
    v.w = lds[(kb + 3) * 516 + n];
    outp[nb * 64 + l] = v;                     // 16B/lane, lanes consecutive
  }
}

// ---------------------------------------------------------------------------
// Fused MLP v6: BM=128, 1024 threads (16 waves), 1 block/CU, 4 waves/SIMD.
// Wave w: row-half rh=w&1 (rows rh*64..+63), col-strip wc=w>>1 (cols
// wc*64..+63). acc[4][4] = 64 AGPR.
// SPILL FIX vs v5: gemm K-loop is a RUNTIME loop (2 chunks/iter, bA/bB role
// swap, no copies, '#pragma unroll 1') -- full unroll let the scheduler hoist
// loads across chunks and spill past the 128-reg/wave cap (R3/R4: 135-172 MB
// scratch WRITE). R0's runtime loop with identical reg shape had zero spill.
// A buffer FRAGMENT-MAJOR, (mb,kt) order: unit(mb,kt,lane) at
// (mb*16384 + kt*1024 + lane*16); ds_read offsets m*16384+{0,1024} are all
// 16-bit immediates off one base VGPR (advanced +2048B/iter).
// Block map: all 32 CUs of an XCD run the same expert concurrently.
// ---------------------------------------------------------------------------
__global__ __launch_bounds__(1024, 4) void mlp_kernel(
    const float* __restrict__ theta, const float* __restrict__ x,
    const short8* __restrict__ wcat, const short8* __restrict__ whf,
    const float* __restrict__ b1, const float* __restrict__ a1,
    const float* __restrict__ bh, const float* __restrict__ ah,
    const float* __restrict__ Wo, const float* __restrict__ bo,
    float* __restrict__ out) {
  __shared__ __align__(16) char smA[8 * 16 * 64 * 16];   // 131072 B, 1 block/CU
  const int tid = threadIdx.x;
  const int bid = blockIdx.x;
  const int xcd = bid & 7;
  const int t8  = bid >> 3;                       // per-XCD sequence 0..127
  const int e   = xcd * 4 + (t8 >> 5);            // 32 consecutive blocks/expert
  const int m0  = (t8 & 31) * BM;
  const int w   = tid >> 6, l = tid & 63, l16 = l & 15, quad = l >> 4;
  const int rh  = w & 1;                          // row half (0: rows 0-63)
  const int wc  = w >> 1;                         // col strip (64 cols)

  // ---- stage A0 = [theta | x] bf16, directly in fragment order ----
  // g: lane=g&63, mb=(g>>6)&7, kt=g>>9; row = mb*16+(lane&15),
  // k = kt*32 + (lane>>4)*8 .. +7  (kt==0 -> theta cols, else x cols).
  for (int g = tid; g < 9 * 512; g += 1024) {
    int lane = g & 63, mb = (g >> 6) & 7, kt = g >> 9;
    int row  = m0 + mb * 16 + (lane & 15);
    int ks   = (lane >> 4) * 8;
    const float* src = (kt == 0)
                           ? (theta + (size_t)row * T_SZ + ks)
                           : (x + (size_t)row * X_SZ + (kt - 1) * 32 + ks);
    float4 a = *(const float4*)src;
    float4 b = *(const float4*)(src + 4);
    *(uint4*)(smA + mb * 16384 + kt * 1024 + lane * 16) =
        make_uint4(pk2(a.x, a.y), pk2(a.z, a.w), pk2(b.x, b.y), pk2(b.z, b.w));
  }
  __syncthreads();

  floatx4 acc[4][4];
  const int u0 = wc * 256 + l;                    // weight unit index (nb=wc*4)
  const char* dsb0 = smA + rh * 65536 + l * 16;   // A-frag base (chunk 0)

  // GEMM over nkt K-chunks of 32. Runtime loop, 2 chunks/iter, bA/bB swap.
  auto gemm = [&](const short8* wbase, int nkt) {
#pragma unroll
    for (int m = 0; m < 4; ++m)
#pragma unroll
      for (int i = 0; i < 4; ++i) acc[m][i] = (floatx4)(0.f);
    short8 bA[4], bB[4];
    const short8* wu = wbase;                     // uniform -> SGPR base
#pragma unroll
    for (int i = 0; i < 4; ++i) bA[i] = wu[u0 + i * 64];   // chunk 0
    const char* dsb = dsb0;
    const int half = nkt >> 1;
#pragma unroll 1
    for (int j = 0; j < half; ++j) {
      // prefetch odd chunk 2j+1 into bB (always < nkt inside this loop)
#pragma unroll
      for (int i = 0; i < 4; ++i) bB[i] = wu[2048 + u0 + i * 64];
      // compute chunk 2j with bA
      {
        short8 af[4];
#pragma unroll
        for (int m = 0; m < 4; ++m)
          af[m] = *(const short8*)(dsb + m * 16384);
#pragma unroll
        for (int m = 0; m < 4; ++m)
#pragma unroll
          for (int i = 0; i < 4; ++i)
            acc[m][i] = __builtin_amdgcn_mfma_f32_16x16x32_bf16(
                af[m], bA[i], acc[m][i], 0, 0, 0);
      }
      // prefetch chunk 2j+2 into bA (clamped at the end; uniform select)
      const short8* wn = (2 * j + 2 < nkt) ? wu + 4096 : wu;
#pragma unroll
      for (int i = 0; i < 4; ++i) bA[i] = wn[u0 + i * 64];
      // compute chunk 2j+1 with bB
      {
        short8 af[4];
#pragma unroll
        for (int m = 0; m < 4; ++m)
          af[m] = *(const short8*)(dsb + m * 16384 + 1024);
#pragma unroll
        for (int m = 0; m < 4; ++m)
#pragma unroll
          for (int i = 0; i < 4; ++i)
            acc[m][i] = __builtin_amdgcn_mfma_f32_16x16x32_bf16(
                af[m], bB[i], acc[m][i], 0, 0, 0);
      }
      wu += 4096;
      dsb += 2048;
    }
    if (nkt & 1) {                                // tail chunk nkt-1 (in bA)
      short8 af[4];
#pragma unroll
      for (int m = 0; m < 4; ++m)
        af[m] = *(const short8*)(dsb + m * 16384);
#pragma unroll
      for (int m = 0; m < 4; ++m)
#pragma unroll
        for (int i = 0; i < 4; ++i)
          acc[m][i] = __builtin_amdgcn_mfma_f32_16x16x32_bf16(
              af[m], bA[i], acc[m][i], 0, 0, 0);
    }
  };

  // bias + PReLU + bf16 pair-pack (shfl_xor 1) + write into fragment-major A.
  // Value (R = rh*64+mb*16+quad*4+r, C = wc*64+i*16+l16) -> unit
  // mb' = rh*4+mb, kt' = wc*2+(i>>1), lane' = (R&15) + ((i*2+(l16>>3))&3)*16,
  // byte-in-lane (l16&6)*2.
  auto epi_store = [&](const float* bias, const float* slope) {
    float bb[4], aa[4];
#pragma unroll
    for (int i = 0; i < 4; ++i) {
      int col = wc * 64 + i * 16 + l16;
      bb[i] = bias[col];
      aa[i] = slope[col];
    }
    __syncthreads();   // everyone done READING A before we overwrite
#pragma unroll
    for (int mb = 0; mb < 4; ++mb) {
#pragma unroll
      for (int i = 0; i < 4; ++i) {
        unsigned dw[4];
#pragma unroll
        for (int r = 0; r < 4; ++r) {
          float v = acc[mb][i][r] + bb[i];
          v = v >= 0.f ? v : aa[i] * v;
          float o  = __shfl_xor(v, 1, 64);
          float lo = (l16 & 1) ? o : v;
          float hi = (l16 & 1) ? v : o;
          dw[r] = pk2(lo, hi);
        }
        int rbase = (l16 & 1) * 2;               // even lanes rows 0,1; odd 2,3
        int mbp   = rh * 4 + mb;
        int ktp   = wc * 2 + (i >> 1);
        int lhi   = ((i * 2 + (l16 >> 3)) & 3) * 16;
        char* ubase = smA + mbp * 16384 + ktp * 1024 + (l16 & 6) * 2;
#pragma unroll
        for (int rr = 0; rr < 2; ++rr) {
          int lane_p = (quad * 4 + rbase + rr) + lhi;
          *(unsigned*)(ubase + lane_p * 16) = dw[rbase + rr];
        }
      }
    }
    __syncthreads();
  };

  // ---- layer 1: K = 288 (9 chunks) ----
  gemm(wcat + (size_t)e * 9 * 2048, 9);
  epi_store(b1 + (size_t)e * H_SZ, a1 + (size_t)e * H_SZ);
  // ---- hidden layer 0: K = 512 (16 chunks) ----
  gemm(whf + (size_t)e * 16 * 2048, 16);
  epi_store(bh + (size_t)e * H_SZ, ah + (size_t)e * H_SZ);
  // ---- hidden layer 1 + fused output dot (fp32, no bf16 rounding) ----
  gemm(whf + (size_t)(E_SZ + e) * 16 * 2048, 16);
  {
    float bb[4], aa[4], wo[4];
#pragma unroll
    for (int i = 0; i < 4; ++i) {
      int col = wc * 64 + i * 16 + l16;
      bb[i] = bh[(size_t)(E_SZ + e) * H_SZ + col];
      aa[i] = ah[(size_t)(E_SZ + e) * H_SZ + col];
      wo[i] = Wo[(size_t)e * H_SZ + col];
    }
    float ps[4][4];
#pragma unroll
    for (int m = 0; m < 4; ++m)
#pragma unroll
      for (int r = 0; r < 4; ++r) ps[m][r] = 0.f;
#pragma unroll
    for (int m = 0; m < 4; ++m)
#pragma unroll
      for (int i = 0; i < 4; ++i)
#pragma unroll
        for (int r = 0; r < 4; ++r) {
          float v = acc[m][i][r] + bb[i];
          v = v >= 0.f ? v : aa[i] * v;
          ps[m][r] += v * wo[i];
        }
    // reduce over the 16 lanes of each quad (cols within this wave's strip)
#pragma unroll
    for (int d = 1; d < 16; d <<= 1)
#pragma unroll
      for (int m = 0; m < 4; ++m)
#pragma unroll
        for (int r = 0; r < 4; ++r) ps[m][r] += __shfl_xor(ps[m][r], d, 64);
    __syncthreads();                 // done reading A; reuse its storage
    float* scratch = (float*)smA;    // [128 rows][8 col-strips]
    if (l16 == 0) {
#pragma unroll
      for (int m = 0; m < 4; ++m)
#pragma unroll
        for (int r = 0; r < 4; ++r)
          scratch[(rh * 64 + m * 16 + quad * 4 + r) * 8 + wc] = ps[m][r];
    }
    __syncthreads();
    if (tid < BM) {
      float s = 0.f;
#pragma unroll
      for (int ww = 0; ww < 8; ++ww) s += scratch[tid * 8 + ww];
      out[(size_t)(m0 + tid) * E_SZ + e] = s + bo[e];
    }
  }
}

// ---------------------------------------------------------------------------
extern "C" void kernel_launch(void* const* d_in, const int* in_sizes, int n_in,
                              void* d_out, int out_size, void* d_ws, size_t ws_size,
                              hipStream_t stream) {
  const float* theta = (const float*)d_in[0];
  const float* x     = (const float*)d_in[1];
  const int*   masks = (const int*)d_in[2];
  const float* W1t   = (const float*)d_in[3];
  const float* W1x   = (const float*)d_in[4];
  const float* b1    = (const float*)d_in[5];
  const float* a1    = (const float*)d_in[6];
  const float* Wh    = (const float*)d_in[7];
  const float* bh    = (const float*)d_in[8];
  const float* ah    = (const float*)d_in[9];
  const float* Wo    = (const float*)d_in[10];
  const float* bo    = (const float*)d_in[11];
  float* out = (float*)d_out;

  // ws layout: [0, 9.4MB) layer-1 frags; [9.4MB, 43MB) hidden frags.
  uint4* wcat = (uint4*)d_ws;
  uint4* whf  = (uint4*)((char*)d_ws + (size_t)E_SZ * 9 * 2048 * 16);

  // 288 layer-1 chunks + 1024 hidden chunks, one block each
  prep_kernel<<<1312, 256, 0, stream>>>(W1t, W1x, masks, Wh, wcat, whf);
  // 1024 blocks: 32 m-tiles x 32 experts, 1024 threads each
  mlp_kernel<<<1024, 1024, 0, stream>>>(theta, x, (const short8*)wcat,
                                        (const short8*)whf, b1, a1, bh, ah, Wo,
                                        bo, out);
}